// Round 5
// baseline (416.839 us; speedup 1.0000x reference)
//
#include <hip/hip_runtime.h>
#include <hip/hip_bf16.h>

#define BB 64
#define SS 2048
#define DD 512
#define MTOT (BB * SS)          // 131072 rows

typedef __attribute__((ext_vector_type(8))) short short8;            // 8 bf16
typedef __attribute__((ext_vector_type(8))) unsigned short ushort8;
typedef __attribute__((ext_vector_type(4))) float f32x4;

// fp32->bf16 RNE; compiler fuses pairs into v_cvt_pk_bf16_f32
__device__ __forceinline__ short f2bf(float f){
  __hip_bfloat16 h = __float2bfloat16(f);
  return *reinterpret_cast<short*>(&h);
}

__device__ __forceinline__ short8 pack8(float4 a, float4 b){
  short8 u;
  u[0]=f2bf(a.x); u[1]=f2bf(a.y); u[2]=f2bf(a.z); u[3]=f2bf(a.w);
  u[4]=f2bf(b.x); u[5]=f2bf(b.y); u[6]=f2bf(b.z); u[7]=f2bf(b.w);
  return u;
}

// ---- kernel 1: W1 fp32 -> bf16, plain row-major [e][d] ----
__global__ void cvt_w1_kernel(const float* __restrict__ W1, unsigned short* __restrict__ W1b){
  int i = blockIdx.x * blockDim.x + threadIdx.x;   // 32768 threads x 8 elems
  const float* src = W1 + (size_t)i * 8;
  float4 f0 = *(const float4*)src;
  float4 f1 = *(const float4*)(src + 4);
  *(short8*)(W1b + (size_t)i * 8) = pack8(f0, f1);
}

// ---- kernel 2: scores = sum_e tanh(x@W1^T + b1)[.,e] * w2[e] ----
// Barrier-free direct-from-cache GEMM. Block = 512 thr / 8 waves, 64 rows.
// Wave wid owns e in [wid*64,+64): per-wave 64x64 tile (acc[4][4]).
// A: fp32 from x via L1/L2 (8-wave dup on shared rows), cvt_pk to bf16.
// B: bf16 W1b rows from L2 (512KB, resident). All loads = base + imm offset.
// No LDS in the K-loop; raw s_barrier (no drain) every 2 steps for convergence.
__launch_bounds__(512, 4)
__global__ void scores_kernel(const float* __restrict__ x,
                              const unsigned short* __restrict__ W1b,
                              const float* __restrict__ b1,
                              const float* __restrict__ w2,
                              float* __restrict__ scorep){
  __shared__ float psum[8 * 64];

  const int t    = threadIdx.x;
  const int lane = t & 63;
  const int wid  = t >> 6;
  const int m0   = blockIdx.x * 64;
  const int arow = lane & 15;          // A row / B col within 16
  const int kgrp = lane >> 4;          // k sub-offset *8

  f32x4 acc[4][4];
  #pragma unroll
  for (int mt = 0; mt < 4; ++mt)
    #pragma unroll
    for (int et = 0; et < 4; ++et)
      acc[mt][et] = (f32x4){0.f, 0.f, 0.f, 0.f};

  // fixed per-lane bases; all K-loop loads are imm offsets off these
  const float* ab0 = x + (size_t)(m0 +  0 + arow) * DD + kgrp * 8;
  const float* ab1 = x + (size_t)(m0 + 16 + arow) * DD + kgrp * 8;
  const float* ab2 = x + (size_t)(m0 + 32 + arow) * DD + kgrp * 8;
  const float* ab3 = x + (size_t)(m0 + 48 + arow) * DD + kgrp * 8;
  const int e0 = (wid << 6) + arow;
  const unsigned short* bb0 = W1b + (size_t)(e0 +  0) * DD + kgrp * 8;
  const unsigned short* bb1 = W1b + (size_t)(e0 + 16) * DD + kgrp * 8;
  const unsigned short* bb2 = W1b + (size_t)(e0 + 32) * DD + kgrp * 8;
  const unsigned short* bb3 = W1b + (size_t)(e0 + 48) * DD + kgrp * 8;

  #pragma unroll
  for (int s = 0; s < 16; ++s){
    const int ao = s * 32;             // fp32 elems: 128B per step
    short8 af[4], bf[4];
    {
      float4 f0, f1;
      f0 = *(const float4*)(ab0 + ao); f1 = *(const float4*)(ab0 + ao + 4); af[0] = pack8(f0, f1);
      f0 = *(const float4*)(ab1 + ao); f1 = *(const float4*)(ab1 + ao + 4); af[1] = pack8(f0, f1);
      f0 = *(const float4*)(ab2 + ao); f1 = *(const float4*)(ab2 + ao + 4); af[2] = pack8(f0, f1);
      f0 = *(const float4*)(ab3 + ao); f1 = *(const float4*)(ab3 + ao + 4); af[3] = pack8(f0, f1);
    }
    bf[0] = *(const short8*)(bb0 + ao);
    bf[1] = *(const short8*)(bb1 + ao);
    bf[2] = *(const short8*)(bb2 + ao);
    bf[3] = *(const short8*)(bb3 + ao);

    #pragma unroll
    for (int mt = 0; mt < 4; ++mt)
      #pragma unroll
      for (int et = 0; et < 4; ++et)
        acc[mt][et] = __builtin_amdgcn_mfma_f32_16x16x32_bf16(af[mt], bf[et], acc[mt][et], 0, 0, 0);

    // convergence barrier (raw: no waitcnt drain) to keep waves' A reads L1-hot
    if ((s & 1) == 1 && s < 15) __builtin_amdgcn_s_barrier();
  }

  // ---- epilogue: tanh + dot(w2), reduce over e ----
  float ps[4][4];
  #pragma unroll
  for (int mt = 0; mt < 4; ++mt)
    #pragma unroll
    for (int i = 0; i < 4; ++i) ps[mt][i] = 0.f;

  #pragma unroll
  for (int et = 0; et < 4; ++et){
    int e = (wid << 6) + (et << 4) + arow;     // C/D col = lane&15
    float b1v = b1[e];
    float w2v = w2[e];
    #pragma unroll
    for (int mt = 0; mt < 4; ++mt){
      #pragma unroll
      for (int i = 0; i < 4; ++i){
        float g = acc[mt][et][i] + b1v;
        g = fminf(15.f, fmaxf(-15.f, g));
        float ex = __expf(2.f * g);
        ps[mt][i] += (1.f - 2.f / (ex + 1.f)) * w2v;   // tanh(g)*w2
      }
    }
  }
  #pragma unroll
  for (int mt = 0; mt < 4; ++mt)
    #pragma unroll
    for (int i = 0; i < 4; ++i){
      float v = ps[mt][i];
      v += __shfl_xor(v, 1);
      v += __shfl_xor(v, 2);
      v += __shfl_xor(v, 4);
      v += __shfl_xor(v, 8);
      ps[mt][i] = v;
    }
  if ((lane & 15) == 0){
    #pragma unroll
    for (int mt = 0; mt < 4; ++mt)
      #pragma unroll
      for (int i = 0; i < 4; ++i)
        psum[wid * 64 + mt * 16 + (lane >> 4) * 4 + i] = ps[mt][i];
  }
  __syncthreads();
  if (t < 64){
    float ssum = 0.f;
    #pragma unroll
    for (int w = 0; w < 8; ++w) ssum += psum[w * 64 + t];
    scorep[m0 + t] = ssum;    // pre-softmax; b2 softmax-invariant
  }
}

// ---- kernel 3: row softmax -> w ----
__global__ void softmax_kernel(const float* __restrict__ scorep, float* __restrict__ wout){
  const int b = blockIdx.x;
  const int t = threadIdx.x;                 // 256
  float v[8];
  #pragma unroll
  for (int i = 0; i < 8; ++i) v[i] = scorep[(size_t)b * SS + t + i * 256];
  float m = v[0];
  #pragma unroll
  for (int i = 1; i < 8; ++i) m = fmaxf(m, v[i]);
  #pragma unroll
  for (int msk = 32; msk >= 1; msk >>= 1) m = fmaxf(m, __shfl_xor(m, msk));
  __shared__ float redm[4], reds[4];
  if ((t & 63) == 0) redm[t >> 6] = m;
  __syncthreads();
  m = fmaxf(fmaxf(redm[0], redm[1]), fmaxf(redm[2], redm[3]));
  float s = 0.f;
  #pragma unroll
  for (int i = 0; i < 8; ++i){ v[i] = __expf(v[i] - m); s += v[i]; }
  #pragma unroll
  for (int msk = 32; msk >= 1; msk >>= 1) s += __shfl_xor(s, msk);
  if ((t & 63) == 0) reds[t >> 6] = s;
  __syncthreads();
  s = reds[0] + reds[1] + reds[2] + reds[3];
  float inv = 1.f / s;
  #pragma unroll
  for (int i = 0; i < 8; ++i) wout[(size_t)b * SS + t + i * 256] = v[i] * inv;
}

// ---- kernel 4: ctx partials (fp32 x, no atomics) ----
__global__ void ctx_partial_kernel(const float* __restrict__ x, const float* __restrict__ wout,
                                   float* __restrict__ ctxp){
  __shared__ float red[4][512];
  const int t   = threadIdx.x;
  const int sub = t >> 7;                    // 0..3 (wave-uniform)
  const int dt  = t & 127;                   // d = dt*4
  const int b   = blockIdx.x >> 3;
  const int sc  = blockIdx.x & 7;
  const float* xb = x + (size_t)b * SS * DD;
  const int s0 = sc * 256 + sub * 64;
  float4 acc = {0.f, 0.f, 0.f, 0.f};
  for (int s = s0; s < s0 + 64; ++s){
    float wv = wout[(size_t)b * SS + s];     // wave-uniform -> scalar load
    float4 xv = *(const float4*)(xb + (size_t)s * DD + dt * 4);
    acc.x += wv * xv.x; acc.y += wv * xv.y; acc.z += wv * xv.z; acc.w += wv * xv.w;
  }
  *(float4*)&red[sub][dt * 4] = acc;
  __syncthreads();
  if (t < 128){
    float4 r0 = *(const float4*)&red[0][t * 4];
    float4 r1 = *(const float4*)&red[1][t * 4];
    float4 r2 = *(const float4*)&red[2][t * 4];
    float4 r3 = *(const float4*)&red[3][t * 4];
    float4 o = { r0.x+r1.x+r2.x+r3.x, r0.y+r1.y+r2.y+r3.y,
                 r0.z+r1.z+r2.z+r3.z, r0.w+r1.w+r2.w+r3.w };
    *(float4*)&ctxp[((size_t)(b * 8 + sc)) * DD + t * 4] = o;
  }
}

// ---- kernel 5: reduce ctx partials -> d_out ----
__global__ void ctx_reduce_kernel(const float* __restrict__ ctxp, float* __restrict__ ctx){
  int i = blockIdx.x * blockDim.x + threadIdx.x;   // 32768
  int b = i >> 9;
  int d = i & 511;
  float s = 0.f;
  #pragma unroll
  for (int sc = 0; sc < 8; ++sc) s += ctxp[((size_t)(b * 8 + sc)) * DD + d];
  ctx[(size_t)b * DD + d] = s;
}

extern "C" void kernel_launch(void* const* d_in, const int* in_sizes, int n_in,
                              void* d_out, int out_size, void* d_ws, size_t ws_size,
                              hipStream_t stream){
  const float* x  = (const float*)d_in[0];
  const float* W1 = (const float*)d_in[1];
  const float* b1 = (const float*)d_in[2];
  const float* w2 = (const float*)d_in[3];
  // d_in[4] = b2: softmax-invariant, unused.

  float* ctx  = (float*)d_out;                         // [64*512]
  float* wout = (float*)d_out + BB * DD;               // [64*2048]

  // ws layout (phase-disjoint reuse):
  //   scores phase: W1b [0, 512K), scorep [512K, 1M)
  //   ctx phase:    ctxp [0, 1M)  (W1b/scorep dead by then; same-stream order)
  unsigned short* W1b = (unsigned short*)d_ws;
  float* scorep = (float*)((char*)d_ws + (512u << 10));
  float* ctxp   = (float*)d_ws;

  hipLaunchKernelGGL(cvt_w1_kernel,      dim3(128),  dim3(256), 0, stream, W1, W1b);
  hipLaunchKernelGGL(scores_kernel,      dim3(2048), dim3(512), 0, stream, x, W1b, b1, w2, scorep);
  hipLaunchKernelGGL(softmax_kernel,     dim3(64),   dim3(256), 0, stream, scorep, wout);
  hipLaunchKernelGGL(ctx_partial_kernel, dim3(512),  dim3(512), 0, stream, x, wout, ctxp);
  hipLaunchKernelGGL(ctx_reduce_kernel,  dim3(128),  dim3(256), 0, stream, ctxp, ctx);
}

// Round 6
// 227.892 us; speedup vs baseline: 1.8291x; 1.8291x over previous
//
#include <hip/hip_runtime.h>
#include <hip/hip_bf16.h>

#define BB 64
#define SS 2048
#define DD 512
#define MTOT (BB * SS)          // 131072 rows

typedef __attribute__((ext_vector_type(8))) short short8;            // 8 bf16
typedef __attribute__((ext_vector_type(4))) float f32x4;

// fp32->bf16 RNE; compiler fuses pairs into v_cvt_pk_bf16_f32
__device__ __forceinline__ short f2bf(float f){
  __hip_bfloat16 h = __float2bfloat16(f);
  return *reinterpret_cast<short*>(&h);
}

__device__ __forceinline__ short8 pack8(float4 a, float4 b){
  short8 u;
  u[0]=f2bf(a.x); u[1]=f2bf(a.y); u[2]=f2bf(a.z); u[3]=f2bf(a.w);
  u[4]=f2bf(b.x); u[5]=f2bf(b.y); u[6]=f2bf(b.z); u[7]=f2bf(b.w);
  return u;
}

// ---- kernel 1: W1 fp32 -> bf16, plain row-major [e][d] ----
__global__ void cvt_w1_kernel(const float* __restrict__ W1, unsigned short* __restrict__ W1b){
  int i = blockIdx.x * blockDim.x + threadIdx.x;   // 32768 threads x 8 elems
  const float* src = W1 + (size_t)i * 8;
  float4 f0 = *(const float4*)src;
  float4 f1 = *(const float4*)(src + 4);
  *(short8*)(W1b + (size_t)i * 8) = pack8(f0, f1);
}

// ---- kernel 2: scores = sum_e tanh(x@W1^T + b1)[.,e] * w2[e] ----
// BM=64, BN=512 (x read once), BK=32, 16 steps, 512 thr / 8 waves.
// Wave wid owns e in [wid*64,+64): 64x64 tile, acc[4][4].
// B: direct L2->reg, double-buffered one step ahead (no LDS for B).
// A: reg-load at s for step s+2; cvt+ds_write at s+1; ds_read at s+2
//    (3 LDS buffers, granule-swizzled). Raw s_barrier + lgkmcnt(0) only —
//    vmem stays in flight across barriers (counted waits are per-reg-use).
__launch_bounds__(512)
__global__ void scores_kernel(const float* __restrict__ x,
                              const unsigned short* __restrict__ W1b,
                              const float* __restrict__ b1v_,
                              const float* __restrict__ w2,
                              float* __restrict__ scorep){
  __shared__ __align__(16) unsigned short abuf[3][2048];   // 3 x 4KB bf16 A tiles
  __shared__ float psum[8 * 64];

  const int t    = threadIdx.x;
  const int lane = t & 63;
  const int wid  = t >> 6;
  const int m0   = blockIdx.x * 64;
  const int arow = lane & 15;          // A row / B col within 16
  const int kgrp = lane >> 4;          // k sub-offset *8

  f32x4 acc[4][4];
  #pragma unroll
  for (int mt = 0; mt < 4; ++mt)
    #pragma unroll
    for (int et = 0; et < 4; ++et)
      acc[mt][et] = (f32x4){0.f, 0.f, 0.f, 0.f};

  // A staging (t<256): row = t>>2, kc = t&3; granule swizzle kc*64+(row^kc)
  const int srow = t >> 2;
  const int skc  = t & 3;
  const float* asrc = x + (size_t)(m0 + srow) * DD + skc * 8;
  const int awoff = ((skc << 6) + (srow ^ skc)) << 4;

  // B bases: 4 fixed per-lane pointers, step offset is an immediate
  const int e0 = (wid << 6) + arow;
  const unsigned short* bp0 = W1b + (size_t)(e0 +  0) * DD + kgrp * 8;
  const unsigned short* bp1 = W1b + (size_t)(e0 + 16) * DD + kgrp * 8;
  const unsigned short* bp2 = W1b + (size_t)(e0 + 32) * DD + kgrp * 8;
  const unsigned short* bp3 = W1b + (size_t)(e0 + 48) * DD + kgrp * 8;

  short8 breg[2][4];
  float4 areg[2][2];

  // ---- prologue: A(0) immediate; B(0); A(1) ----
  float4 p0, p1;
  if (t < 256){
    p0 = *(const float4*)asrc;
    p1 = *(const float4*)(asrc + 4);
  }
  breg[0][0] = *(const short8*)bp0;
  breg[0][1] = *(const short8*)bp1;
  breg[0][2] = *(const short8*)bp2;
  breg[0][3] = *(const short8*)bp3;
  if (t < 256){
    areg[1][0] = *(const float4*)(asrc + 32);    // A(1)
    areg[1][1] = *(const float4*)(asrc + 36);
    *(short8*)((char*)&abuf[0][0] + awoff) = pack8(p0, p1);
  }
  asm volatile("s_waitcnt lgkmcnt(0)" ::: "memory");
  __builtin_amdgcn_s_barrier();
  __builtin_amdgcn_sched_barrier(0);

  // ---- main loop: 16 k-steps of 32, fully unrolled (static buffer indices) ----
  #pragma unroll
  for (int s = 0; s < 16; ++s){
    // 1. B(s+1) -> other reg buffer (L2-resident, one step of cover)
    if (s < 15){
      breg[(s + 1) & 1][0] = *(const short8*)(bp0 + (s + 1) * 32);
      breg[(s + 1) & 1][1] = *(const short8*)(bp1 + (s + 1) * 32);
      breg[(s + 1) & 1][2] = *(const short8*)(bp2 + (s + 1) * 32);
      breg[(s + 1) & 1][3] = *(const short8*)(bp3 + (s + 1) * 32);
    }
    // 2. A(s+2) global -> regs (HBM, two steps of cover)
    if (s < 14 && t < 256){
      areg[s & 1][0] = *(const float4*)(asrc + (s + 2) * 32);
      areg[s & 1][1] = *(const float4*)(asrc + (s + 2) * 32 + 4);
    }
    // 3. A fragments from LDS
    short8 af[4];
    #pragma unroll
    for (int mt = 0; mt < 4; ++mt){
      int row = mt * 16 + arow;
      af[mt] = *(const short8*)((char*)&abuf[s % 3][0] + (((kgrp << 6) + (row ^ kgrp)) << 4));
    }
    // 4. MFMA
    __builtin_amdgcn_s_setprio(1);
    #pragma unroll
    for (int mt = 0; mt < 4; ++mt)
      #pragma unroll
      for (int et = 0; et < 4; ++et)
        acc[mt][et] = __builtin_amdgcn_mfma_f32_16x16x32_bf16(af[mt], breg[s & 1][et], acc[mt][et], 0, 0, 0);
    __builtin_amdgcn_s_setprio(0);
    // 5. cvt A(s+1) (loaded at s-1) -> LDS buffer (s+1)%3
    if (s < 15 && t < 256)
      *(short8*)((char*)&abuf[(s + 1) % 3][0] + awoff) = pack8(areg[(s + 1) & 1][0], areg[(s + 1) & 1][1]);
    // 6. raw barrier: LDS visibility only, vmem stays in flight
    asm volatile("s_waitcnt lgkmcnt(0)" ::: "memory");
    __builtin_amdgcn_s_barrier();
    __builtin_amdgcn_sched_barrier(0);
  }

  // ---- epilogue: tanh + dot(w2), reduce over e ----
  float ps[4][4];
  #pragma unroll
  for (int mt = 0; mt < 4; ++mt)
    #pragma unroll
    for (int i = 0; i < 4; ++i) ps[mt][i] = 0.f;

  #pragma unroll
  for (int et = 0; et < 4; ++et){
    int e = (wid << 6) + (et << 4) + arow;     // C/D col = lane&15
    float b1v = b1v_[e];
    float w2v = w2[e];
    #pragma unroll
    for (int mt = 0; mt < 4; ++mt){
      #pragma unroll
      for (int i = 0; i < 4; ++i){
        float g = acc[mt][et][i] + b1v;
        g = fminf(15.f, fmaxf(-15.f, g));
        float ex = __expf(2.f * g);
        ps[mt][i] += (1.f - 2.f / (ex + 1.f)) * w2v;   // tanh(g)*w2
      }
    }
  }
  #pragma unroll
  for (int mt = 0; mt < 4; ++mt)
    #pragma unroll
    for (int i = 0; i < 4; ++i){
      float v = ps[mt][i];
      v += __shfl_xor(v, 1);
      v += __shfl_xor(v, 2);
      v += __shfl_xor(v, 4);
      v += __shfl_xor(v, 8);
      ps[mt][i] = v;
    }
  if ((lane & 15) == 0){
    #pragma unroll
    for (int mt = 0; mt < 4; ++mt)
      #pragma unroll
      for (int i = 0; i < 4; ++i)
        psum[wid * 64 + mt * 16 + (lane >> 4) * 4 + i] = ps[mt][i];
  }
  __syncthreads();
  if (t < 64){
    float ssum = 0.f;
    #pragma unroll
    for (int w = 0; w < 8; ++w) ssum += psum[w * 64 + t];
    scorep[m0 + t] = ssum;    // pre-softmax; b2 softmax-invariant
  }
}

// ---- kernel 3: row softmax -> w ----
__global__ void softmax_kernel(const float* __restrict__ scorep, float* __restrict__ wout){
  const int b = blockIdx.x;
  const int t = threadIdx.x;                 // 256
  float v[8];
  #pragma unroll
  for (int i = 0; i < 8; ++i) v[i] = scorep[(size_t)b * SS + t + i * 256];
  float m = v[0];
  #pragma unroll
  for (int i = 1; i < 8; ++i) m = fmaxf(m, v[i]);
  #pragma unroll
  for (int msk = 32; msk >= 1; msk >>= 1) m = fmaxf(m, __shfl_xor(m, msk));
  __shared__ float redm[4], reds[4];
  if ((t & 63) == 0) redm[t >> 6] = m;
  __syncthreads();
  m = fmaxf(fmaxf(redm[0], redm[1]), fmaxf(redm[2], redm[3]));
  float s = 0.f;
  #pragma unroll
  for (int i = 0; i < 8; ++i){ v[i] = __expf(v[i] - m); s += v[i]; }
  #pragma unroll
  for (int msk = 32; msk >= 1; msk >>= 1) s += __shfl_xor(s, msk);
  if ((t & 63) == 0) reds[t >> 6] = s;
  __syncthreads();
  s = reds[0] + reds[1] + reds[2] + reds[3];
  float inv = 1.f / s;
  #pragma unroll
  for (int i = 0; i < 8; ++i) wout[(size_t)b * SS + t + i * 256] = v[i] * inv;
}

// ---- kernel 4: ctx partials (fp32 x, no atomics; HBM-roofline) ----
__global__ void ctx_partial_kernel(const float* __restrict__ x, const float* __restrict__ wout,
                                   float* __restrict__ ctxp){
  __shared__ float red[4][512];
  const int t   = threadIdx.x;
  const int sub = t >> 7;                    // 0..3 (wave-uniform)
  const int dt  = t & 127;                   // d = dt*4
  const int b   = blockIdx.x >> 3;
  const int sc  = blockIdx.x & 7;
  const float* xb = x + (size_t)b * SS * DD;
  const int s0 = sc * 256 + sub * 64;
  float4 acc = {0.f, 0.f, 0.f, 0.f};
  for (int s = s0; s < s0 + 64; ++s){
    float wv = wout[(size_t)b * SS + s];     // wave-uniform -> scalar load
    float4 xv = *(const float4*)(xb + (size_t)s * DD + dt * 4);
    acc.x += wv * xv.x; acc.y += wv * xv.y; acc.z += wv * xv.z; acc.w += wv * xv.w;
  }
  *(float4*)&red[sub][dt * 4] = acc;
  __syncthreads();
  if (t < 128){
    float4 r0 = *(const float4*)&red[0][t * 4];
    float4 r1 = *(const float4*)&red[1][t * 4];
    float4 r2 = *(const float4*)&red[2][t * 4];
    float4 r3 = *(const float4*)&red[3][t * 4];
    float4 o = { r0.x+r1.x+r2.x+r3.x, r0.y+r1.y+r2.y+r3.y,
                 r0.z+r1.z+r2.z+r3.z, r0.w+r1.w+r2.w+r3.w };
    *(float4*)&ctxp[((size_t)(b * 8 + sc)) * DD + t * 4] = o;
  }
}

// ---- kernel 5: reduce ctx partials -> d_out ----
__global__ void ctx_reduce_kernel(const float* __restrict__ ctxp, float* __restrict__ ctx){
  int i = blockIdx.x * blockDim.x + threadIdx.x;   // 32768
  int b = i >> 9;
  int d = i & 511;
  float s = 0.f;
  #pragma unroll
  for (int sc = 0; sc < 8; ++sc) s += ctxp[((size_t)(b * 8 + sc)) * DD + d];
  ctx[(size_t)b * DD + d] = s;
}

extern "C" void kernel_launch(void* const* d_in, const int* in_sizes, int n_in,
                              void* d_out, int out_size, void* d_ws, size_t ws_size,
                              hipStream_t stream){
  const float* x  = (const float*)d_in[0];
  const float* W1 = (const float*)d_in[1];
  const float* b1 = (const float*)d_in[2];
  const float* w2 = (const float*)d_in[3];
  // d_in[4] = b2: softmax-invariant, unused.

  float* ctx  = (float*)d_out;                         // [64*512]
  float* wout = (float*)d_out + BB * DD;               // [64*2048]

  // ws layout (phase-disjoint reuse):
  //   scores phase: W1b [0, 512K), scorep [512K, 1M)
  //   ctx phase:    ctxp [0, 1M)  (W1b/scorep dead by then; same-stream order)
  unsigned short* W1b = (unsigned short*)d_ws;
  float* scorep = (float*)((char*)d_ws + (512u << 10));
  float* ctxp   = (float*)d_ws;

  hipLaunchKernelGGL(cvt_w1_kernel,      dim3(128),  dim3(256), 0, stream, W1, W1b);
  hipLaunchKernelGGL(scores_kernel,      dim3(2048), dim3(512), 0, stream, x, W1b, b1, w2, scorep);
  hipLaunchKernelGGL(softmax_kernel,     dim3(64),   dim3(256), 0, stream, scorep, wout);
  hipLaunchKernelGGL(ctx_partial_kernel, dim3(512),  dim3(512), 0, stream, x, wout, ctxp);
  hipLaunchKernelGGL(ctx_reduce_kernel,  dim3(128),  dim3(256), 0, stream, ctxp, ctx);
}

// Round 7
// 207.423 us; speedup vs baseline: 2.0096x; 1.0987x over previous
//
#include <hip/hip_runtime.h>
#include <hip/hip_bf16.h>

#define BB 64
#define SS 2048
#define DD 512
#define MTOT (BB * SS)          // 131072 rows

typedef __attribute__((ext_vector_type(8))) short short8;   // 8 bf16
typedef __attribute__((ext_vector_type(4))) short s16x4;    // 4 bf16
typedef __attribute__((ext_vector_type(4))) float f32x4;

// fp32->bf16 RNE; compiler fuses pairs into v_cvt_pk_bf16_f32
__device__ __forceinline__ short f2bf(float f){
  __hip_bfloat16 h = __float2bfloat16(f);
  return *reinterpret_cast<short*>(&h);
}
__device__ __forceinline__ float bf2f(unsigned short u){
  union { unsigned int i; float f; } a; a.i = ((unsigned int)u) << 16;
  return a.f;
}
__device__ __forceinline__ short8 pack8(float4 a, float4 b){
  short8 u;
  u[0]=f2bf(a.x); u[1]=f2bf(a.y); u[2]=f2bf(a.z); u[3]=f2bf(a.w);
  u[4]=f2bf(b.x); u[5]=f2bf(b.y); u[6]=f2bf(b.z); u[7]=f2bf(b.w);
  return u;
}
__device__ __forceinline__ s16x4 pack4(float4 a){
  s16x4 u;
  u[0]=f2bf(a.x); u[1]=f2bf(a.y); u[2]=f2bf(a.z); u[3]=f2bf(a.w);
  return u;
}
__device__ __forceinline__ void gload_lds16(const unsigned short* g, unsigned short* l){
  __builtin_amdgcn_global_load_lds(
      (const __attribute__((address_space(1))) unsigned int*)g,
      (__attribute__((address_space(3))) unsigned int*)l, 16, 0, 0);
}

// ---- kernel 1: W1 fp32 -> bf16, PRE-SWIZZLED per-step tile layout (R3-proven) ----
// granule (s,g): kc=g>>9, holds W1 row e=(g&511)^kc, k-elems [s*32+kc*8, +8).
__global__ void cvt_w1_kernel(const float* __restrict__ W1, unsigned short* __restrict__ W1s){
  int i = blockIdx.x * blockDim.x + threadIdx.x;   // 32768 = 16 steps * 2048 granules
  int s  = i >> 11;
  int g  = i & 2047;
  int kc = g >> 9;
  int e  = (g & 511) ^ kc;
  const float* src = W1 + (size_t)e * DD + s * 32 + kc * 8;
  float4 f0 = *(const float4*)src;
  float4 f1 = *(const float4*)(src + 4);
  *(short8*)(W1s + (size_t)i * 8) = pack8(f0, f1);
}

// ---- kernel 2: fused scores + block-local softmax partial + ctx partial ----
// BM=64 (one b), BN=512, BK=32, 16 steps, 512 thr / 8 waves.
// A: persistent 64KB LDS tile, written slice-by-slice (reg depth-2 prefetch).
// B: gload_lds double-buffer from pre-swizzled W1s (L2).
// Barriers: raw s_barrier + lgkmcnt(0) + counted vmcnt(1) — A-prefetch never drains.
// Epilogue: scores -> local softmax (m,sigma,p) -> ctxp = sum p*x from A-tile.
__launch_bounds__(512, 2)
__global__ void scores_kernel(const float* __restrict__ x,
                              const unsigned short* __restrict__ W1s,
                              const float* __restrict__ b1,
                              const float* __restrict__ w2,
                              float* __restrict__ scorep,
                              float* __restrict__ mpart,
                              float* __restrict__ spart,
                              float* __restrict__ ctxp){
  __shared__ __align__(16) unsigned short Atile[64 * 512];   // 64KB, granule-swizzled
  __shared__ __align__(16) unsigned short Bbuf[2][16384];    // 2 x 32KB
  __shared__ float psum[8 * 64];
  __shared__ float pbuf[64];

  const int t    = threadIdx.x;
  const int lane = t & 63;
  const int wid  = t >> 6;
  const int m0   = blockIdx.x * 64;
  const int arow = lane & 15;
  const int kgrp = lane >> 4;

  f32x4 acc[4][4];
  #pragma unroll
  for (int mt = 0; mt < 4; ++mt)
    #pragma unroll
    for (int et = 0; et < 4; ++et)
      acc[mt][et] = (f32x4){0.f, 0.f, 0.f, 0.f};

  // A staging: all 512 threads, 1 float4/step. r = t>>3, q = t&7.
  const int ar  = t >> 3;
  const int aq  = t & 7;
  const int arx = ar & 7;
  const float* asrc = x + (size_t)(m0 + ar) * DD + aq * 4;
  // A-tile byte offset for (row r, granule c): (r*64 + (c ^ (r&7)))*16
  // staged granule at step s: c = s*4 + (aq>>1), half (aq&1)*8

  // B staging: wave wid covers granules [wid*256, +256) of each 2048-granule step
  const unsigned short* bsrc = W1s + ((size_t)(wid << 8) + lane) * 8;

  float4 a_pre[2];

  // ---- prologue: B(0), A(0), B(1), A(1); cvt A(0) -> slice 0 ----
  #pragma unroll
  for (int j = 0; j < 4; ++j)
    gload_lds16(bsrc + j * 512, &Bbuf[0][((wid << 2) + j) * 512]);
  float4 a0 = *(const float4*)asrc;
  #pragma unroll
  for (int j = 0; j < 4; ++j)
    gload_lds16(bsrc + 16384 + j * 512, &Bbuf[1][((wid << 2) + j) * 512]);
  a_pre[1] = *(const float4*)(asrc + 32);
  {
    s16x4 u = pack4(a0);
    *(s16x4*)((char*)Atile + ((ar * 64 + ((aq >> 1) ^ arx)) << 4) + (aq & 1) * 8) = u;
  }
  asm volatile("s_waitcnt vmcnt(5)" ::: "memory");   // B(0),A(0) done; B(1),A(1) in flight
  asm volatile("s_waitcnt lgkmcnt(0)" ::: "memory");
  __builtin_amdgcn_s_barrier();
  __builtin_amdgcn_sched_barrier(0);

  // ---- main loop: 16 k-steps of 32 ----
  #pragma unroll
  for (int s = 0; s < 16; ++s){
    // issue B(s+1) into freed buffer (freed at end of s-1; s=0 pre-staged)
    if (s >= 1 && s < 15){
      const unsigned short* bs = bsrc + (size_t)(s + 1) * 16384;
      #pragma unroll
      for (int j = 0; j < 4; ++j)
        gload_lds16(bs + j * 512, &Bbuf[(s + 1) & 1][((wid << 2) + j) * 512]);
    }
    // issue A(s+2) reg load (2-step HBM cover; stays in flight across barrier)
    if (s < 14)
      a_pre[s & 1] = *(const float4*)(asrc + (s + 2) * 32);

    // fragment reads
    short8 af[4], bf[4];
    #pragma unroll
    for (int mt = 0; mt < 4; ++mt){
      int row = mt * 16 + arow;
      af[mt] = *(const short8*)((char*)Atile + ((row * 64 + ((s * 4 + kgrp) ^ (row & 7))) << 4));
    }
    #pragma unroll
    for (int et = 0; et < 4; ++et){
      int e = (wid << 6) + (et << 4) + arow;
      bf[et] = *(const short8*)((char*)&Bbuf[s & 1][0] + (((kgrp << 9) + (e ^ kgrp)) << 4));
    }

    __builtin_amdgcn_s_setprio(1);
    #pragma unroll
    for (int mt = 0; mt < 4; ++mt)
      #pragma unroll
      for (int et = 0; et < 4; ++et)
        acc[mt][et] = __builtin_amdgcn_mfma_f32_16x16x32_bf16(af[mt], bf[et], acc[mt][et], 0, 0, 0);
    __builtin_amdgcn_s_setprio(0);

    // cvt A(s+1) (loaded at s-1) -> persistent slice s+1
    if (s < 15){
      s16x4 u = pack4(a_pre[(s + 1) & 1]);
      *(s16x4*)((char*)Atile + ((ar * 64 + (((s + 1) * 4 + (aq >> 1)) ^ arx)) << 4) + (aq & 1) * 8) = u;
    }

    if (s < 15){
      if (s < 14) asm volatile("s_waitcnt vmcnt(1)" ::: "memory");  // leave A(s+2) in flight
      else        asm volatile("s_waitcnt vmcnt(0)" ::: "memory");
      asm volatile("s_waitcnt lgkmcnt(0)" ::: "memory");
      __builtin_amdgcn_s_barrier();
      __builtin_amdgcn_sched_barrier(0);
    }
  }

  // ---- epilogue 1: tanh + dot(w2), reduce over e -> scores ----
  float ps[4][4];
  #pragma unroll
  for (int mt = 0; mt < 4; ++mt)
    #pragma unroll
    for (int i = 0; i < 4; ++i) ps[mt][i] = 0.f;

  #pragma unroll
  for (int et = 0; et < 4; ++et){
    int e = (wid << 6) + (et << 4) + arow;     // C/D col = lane&15
    float b1v = b1[e];
    float w2v = w2[e];
    #pragma unroll
    for (int mt = 0; mt < 4; ++mt){
      #pragma unroll
      for (int i = 0; i < 4; ++i){
        float g = acc[mt][et][i] + b1v;
        g = fminf(15.f, fmaxf(-15.f, g));
        float ex = __expf(2.f * g);
        ps[mt][i] += (1.f - 2.f / (ex + 1.f)) * w2v;   // tanh(g)*w2
      }
    }
  }
  #pragma unroll
  for (int mt = 0; mt < 4; ++mt)
    #pragma unroll
    for (int i = 0; i < 4; ++i){
      float v = ps[mt][i];
      v += __shfl_xor(v, 1);
      v += __shfl_xor(v, 2);
      v += __shfl_xor(v, 4);
      v += __shfl_xor(v, 8);
      ps[mt][i] = v;
    }
  if ((lane & 15) == 0){
    #pragma unroll
    for (int mt = 0; mt < 4; ++mt)
      #pragma unroll
      for (int i = 0; i < 4; ++i)
        psum[wid * 64 + mt * 16 + (lane >> 4) * 4 + i] = ps[mt][i];
  }
  __syncthreads();

  // ---- epilogue 2: local softmax partial (wave 0) ----
  if (t < 64){
    float score = 0.f;
    #pragma unroll
    for (int w = 0; w < 8; ++w) score += psum[w * 64 + t];
    scorep[m0 + t] = score;                  // pre-softmax (b2 softmax-invariant)
    float m = score;
    #pragma unroll
    for (int msk = 32; msk >= 1; msk >>= 1) m = fmaxf(m, __shfl_xor(m, msk));
    float p = __expf(score - m);
    float sg = p;
    #pragma unroll
    for (int msk = 32; msk >= 1; msk >>= 1) sg += __shfl_xor(sg, msk);
    if (t == 0){ mpart[blockIdx.x] = m; spart[blockIdx.x] = sg; }
    pbuf[t] = p;
  }
  __syncthreads();

  // ---- epilogue 3: ctx partial = sum_r p[r] * x[r, d] from A-tile (bf16) ----
  {
    float a = 0.f;
    const int cg = (t >> 3);      // granule col of element d=t
    const int ch = (t & 7) * 2;   // byte within granule
    #pragma unroll 8
    for (int r = 0; r < 64; ++r){
      float pw = pbuf[r];
      unsigned short uxv = *(const unsigned short*)((char*)Atile + ((r * 64 + (cg ^ (r & 7))) << 4) + ch);
      a += pw * bf2f(uxv);
    }
    ctxp[(size_t)blockIdx.x * DD + t] = a;
  }
}

// ---- kernel 3: merge partials -> ctx + w ----
__global__ void merge_kernel(const float* __restrict__ scorep,
                             const float* __restrict__ mpart,
                             const float* __restrict__ spart,
                             const float* __restrict__ ctxp,
                             float* __restrict__ ctx,
                             float* __restrict__ wout){
  const int b = blockIdx.x;      // 64
  const int t = threadIdx.x;     // 512
  float M = -1e30f;
  #pragma unroll
  for (int i = 0; i < 32; ++i) M = fmaxf(M, mpart[b * 32 + i]);
  float Z = 0.f;
  #pragma unroll
  for (int i = 0; i < 32; ++i) Z += spart[b * 32 + i] * __expf(mpart[b * 32 + i] - M);
  float invZ = 1.f / Z;
  float a = 0.f;
  #pragma unroll
  for (int i = 0; i < 32; ++i)
    a += __expf(mpart[b * 32 + i] - M) * ctxp[(size_t)(b * 32 + i) * DD + t];
  ctx[(size_t)b * DD + t] = a * invZ;
  #pragma unroll
  for (int j = 0; j < 4; ++j){
    int s = j * 512 + t;
    wout[(size_t)b * SS + s] = __expf(scorep[(size_t)b * SS + s] - M) * invZ;
  }
}

extern "C" void kernel_launch(void* const* d_in, const int* in_sizes, int n_in,
                              void* d_out, int out_size, void* d_ws, size_t ws_size,
                              hipStream_t stream){
  const float* x  = (const float*)d_in[0];
  const float* W1 = (const float*)d_in[1];
  const float* b1 = (const float*)d_in[2];
  const float* w2 = (const float*)d_in[3];
  // d_in[4] = b2: softmax-invariant, unused.

  float* ctx  = (float*)d_out;                         // [64*512]
  float* wout = (float*)d_out + BB * DD;               // [64*2048]

  // ws: W1s 512K | scorep 512K | mpart 8K | spart 8K | ctxp 4M  (~5MB)
  char* ws = (char*)d_ws;
  unsigned short* W1s = (unsigned short*)ws;
  float* scorep = (float*)(ws + (512u << 10));
  float* mpart  = (float*)(ws + (1024u << 10));
  float* spart  = (float*)(ws + (1024u << 10) + (8u << 10));
  float* ctxp   = (float*)(ws + (1024u << 10) + (16u << 10));

  hipLaunchKernelGGL(cvt_w1_kernel, dim3(128),  dim3(256), 0, stream, W1, W1s);
  hipLaunchKernelGGL(scores_kernel, dim3(2048), dim3(512), 0, stream,
                     x, W1s, b1, w2, scorep, mpart, spart, ctxp);
  hipLaunchKernelGGL(merge_kernel,  dim3(64),   dim3(512), 0, stream,
                     scorep, mpart, spart, ctxp, ctx, wout);
}

// Round 8
// 169.228 us; speedup vs baseline: 2.4632x; 1.2257x over previous
//
#include <hip/hip_runtime.h>
#include <hip/hip_bf16.h>

#define BB 64
#define SS 2048
#define DD 512
#define MTOT (BB * SS)          // 131072 rows

typedef __attribute__((ext_vector_type(8))) short short8;   // 8 bf16
typedef __attribute__((ext_vector_type(4))) short s16x4;    // 4 bf16
typedef __attribute__((ext_vector_type(4))) float f32x4;

// fp32->bf16 RNE; compiler fuses pairs into v_cvt_pk_bf16_f32
__device__ __forceinline__ short f2bf(float f){
  __hip_bfloat16 h = __float2bfloat16(f);
  return *reinterpret_cast<short*>(&h);
}
__device__ __forceinline__ short8 pack8(float4 a, float4 b){
  short8 u;
  u[0]=f2bf(a.x); u[1]=f2bf(a.y); u[2]=f2bf(a.z); u[3]=f2bf(a.w);
  u[4]=f2bf(b.x); u[5]=f2bf(b.y); u[6]=f2bf(b.z); u[7]=f2bf(b.w);
  return u;
}
__device__ __forceinline__ s16x4 pack4(float4 a){
  s16x4 u;
  u[0]=f2bf(a.x); u[1]=f2bf(a.y); u[2]=f2bf(a.z); u[3]=f2bf(a.w);
  return u;
}
__device__ __forceinline__ void gload_lds16(const unsigned short* g, unsigned short* l){
  __builtin_amdgcn_global_load_lds(
      (const __attribute__((address_space(1))) unsigned int*)g,
      (__attribute__((address_space(3))) unsigned int*)l, 16, 0, 0);
}

// ---- kernel 1: W1 fp32 -> bf16, PRE-SWIZZLED per-step tile layout (R3-proven) ----
// granule (s,g): kc=g>>9, holds W1 row e=(g&511)^kc, k-elems [s*32+kc*8, +8).
__global__ void cvt_w1_kernel(const float* __restrict__ W1, unsigned short* __restrict__ W1s){
  int i = blockIdx.x * blockDim.x + threadIdx.x;   // 32768 = 16 steps * 2048 granules
  int s  = i >> 11;
  int g  = i & 2047;
  int kc = g >> 9;
  int e  = (g & 511) ^ kc;
  const float* src = W1 + (size_t)e * DD + s * 32 + kc * 8;
  float4 f0 = *(const float4*)src;
  float4 f1 = *(const float4*)(src + 4);
  *(short8*)(W1s + (size_t)i * 8) = pack8(f0, f1);
}

// ---- kernel 2: scores = sum_e tanh(x@W1^T + b1)[.,e] * w2[e] ----
// BM=64, BN=512, BK=32, 16 steps, 512 thr / 8 waves, wave-tile 64x64 (acc[4][4]).
// A: all-512-thread staging, DEPTH-2 reg prefetch (A(s+2) issued at s, written
//    at s+1), 2 LDS slices of 4KB, swizzle g^((r>>1)&3).
// B: gload_lds double-buffer from pre-swizzled W1s (issued 1 step ahead).
// Barriers: raw s_barrier + lgkmcnt(0) + counted vmcnt(1) — B retires, the
// A-prefetch (issued after B) stays in flight across the barrier.
// LDS 74KB, regs<=128 -> 2 blocks/CU.
__launch_bounds__(512, 4)
__global__ void scores_kernel(const float* __restrict__ x,
                              const unsigned short* __restrict__ W1s,
                              const float* __restrict__ b1,
                              const float* __restrict__ w2,
                              float* __restrict__ scorep){
  __shared__ __align__(16) unsigned short Bbuf[2][16384];  // 2 x 32KB
  __shared__ __align__(16) unsigned short Abuf[2][2048];   // 2 x 4KB
  __shared__ float psum[8 * 64];

  const int t    = threadIdx.x;
  const int lane = t & 63;
  const int wid  = t >> 6;
  const int m0   = blockIdx.x * 64;
  const int arow = lane & 15;
  const int kgrp = lane >> 4;

  f32x4 acc[4][4];
  #pragma unroll
  for (int mt = 0; mt < 4; ++mt)
    #pragma unroll
    for (int et = 0; et < 4; ++et)
      acc[mt][et] = (f32x4){0.f, 0.f, 0.f, 0.f};

  // A staging: all 512 threads, 1 float4/step. r=t>>3 (0..63), q=t&7 (4-col chunk)
  const int ar = t >> 3;
  const int aq = t & 7;
  const float* asrc = x + (size_t)(m0 + ar) * DD + aq * 4;
  // write byte offset: granule g=aq>>1, half h=aq&1, swizzle g^((r>>1)&3)
  const int awoff = ((((ar << 2) + ((aq >> 1) ^ ((ar >> 1) & 3))) << 4) + ((aq & 1) << 3));

  // B staging: wave wid issues 4 gload_lds; source linear in pre-swizzled W1s
  const unsigned short* bsrc = W1s + ((size_t)((wid << 2) << 6) + lane) * 8;

  float4 areg[2];

  // ---- prologue: B(0); A(0); A(1); cvt A(0)->slice0 ----
  #pragma unroll
  for (int j = 0; j < 4; ++j)
    gload_lds16(bsrc + j * 512, &Bbuf[0][((wid << 2) + j) * 512]);
  float4 p0 = *(const float4*)asrc;
  areg[1] = *(const float4*)(asrc + 32);
  *(s16x4*)((char*)&Abuf[0][0] + awoff) = pack4(p0);
  asm volatile("s_waitcnt vmcnt(1)" ::: "memory");   // B(0)+A(0) done; A(1) in flight
  asm volatile("s_waitcnt lgkmcnt(0)" ::: "memory");
  __builtin_amdgcn_s_barrier();
  __builtin_amdgcn_sched_barrier(0);

  // ---- main loop: 16 k-steps of 32, fully unrolled ----
  #pragma unroll
  for (int s = 0; s < 16; ++s){
    // 1. issue B(s+1) gload_lds (retired at this step's barrier)
    if (s < 15){
      const unsigned short* bs = bsrc + (size_t)(s + 1) * 16384;
      #pragma unroll
      for (int j = 0; j < 4; ++j)
        gload_lds16(bs + j * 512, &Bbuf[(s + 1) & 1][((wid << 2) + j) * 512]);
    }
    // 2. issue A(s+2) (stays in flight across this step's barrier)
    if (s < 14)
      areg[s & 1] = *(const float4*)(asrc + (s + 2) * 32);

    // 3. fragment reads
    short8 af[4], bf[4];
    #pragma unroll
    for (int mt = 0; mt < 4; ++mt){
      int row = mt * 16 + arow;
      af[mt] = *(const short8*)((char*)&Abuf[s & 1][0]
                + (((row << 2) + (kgrp ^ ((row >> 1) & 3))) << 4));
    }
    #pragma unroll
    for (int et = 0; et < 4; ++et){
      int e = (wid << 6) + (et << 4) + arow;
      bf[et] = *(const short8*)((char*)&Bbuf[s & 1][0] + (((kgrp << 9) + (e ^ kgrp)) << 4));
    }

    // 4. MFMA
    __builtin_amdgcn_s_setprio(1);
    #pragma unroll
    for (int mt = 0; mt < 4; ++mt)
      #pragma unroll
      for (int et = 0; et < 4; ++et)
        acc[mt][et] = __builtin_amdgcn_mfma_f32_16x16x32_bf16(af[mt], bf[et], acc[mt][et], 0, 0, 0);
    __builtin_amdgcn_s_setprio(0);

    // 5. cvt+write A(s+1) (loaded at step s-1; ~2 steps old -> wait nearly free)
    if (s < 15)
      *(s16x4*)((char*)&Abuf[(s + 1) & 1][0] + awoff) = pack4(areg[(s + 1) & 1]);

    // 6. counted-vmcnt barrier: retire B(s+1), keep A(s+2) in flight
    if (s < 15){
      if (s < 14) asm volatile("s_waitcnt vmcnt(1)" ::: "memory");
      else        asm volatile("s_waitcnt vmcnt(0)" ::: "memory");
      asm volatile("s_waitcnt lgkmcnt(0)" ::: "memory");
      __builtin_amdgcn_s_barrier();
      __builtin_amdgcn_sched_barrier(0);
    }
  }

  // ---- epilogue: tanh + dot(w2), reduce over e ----
  float ps[4][4];
  #pragma unroll
  for (int mt = 0; mt < 4; ++mt)
    #pragma unroll
    for (int i = 0; i < 4; ++i) ps[mt][i] = 0.f;

  #pragma unroll
  for (int et = 0; et < 4; ++et){
    int e = (wid << 6) + (et << 4) + arow;     // C/D col = lane&15
    float b1v = b1[e];
    float w2v = w2[e];
    #pragma unroll
    for (int mt = 0; mt < 4; ++mt){
      #pragma unroll
      for (int i = 0; i < 4; ++i){
        float g = acc[mt][et][i] + b1v;
        g = fminf(15.f, fmaxf(-15.f, g));
        float ex = __expf(2.f * g);
        ps[mt][i] += (1.f - 2.f / (ex + 1.f)) * w2v;   // tanh(g)*w2
      }
    }
  }
  #pragma unroll
  for (int mt = 0; mt < 4; ++mt)
    #pragma unroll
    for (int i = 0; i < 4; ++i){
      float v = ps[mt][i];
      v += __shfl_xor(v, 1);
      v += __shfl_xor(v, 2);
      v += __shfl_xor(v, 4);
      v += __shfl_xor(v, 8);
      ps[mt][i] = v;
    }
  if ((lane & 15) == 0){
    #pragma unroll
    for (int mt = 0; mt < 4; ++mt)
      #pragma unroll
      for (int i = 0; i < 4; ++i)
        psum[wid * 64 + mt * 16 + (lane >> 4) * 4 + i] = ps[mt][i];
  }
  __syncthreads();
  if (t < 64){
    float ssum = 0.f;
    #pragma unroll
    for (int w = 0; w < 8; ++w) ssum += psum[w * 64 + t];
    scorep[m0 + t] = ssum;    // pre-softmax; b2 softmax-invariant
  }
}

// ---- kernel 3: row softmax -> w ----
__global__ void softmax_kernel(const float* __restrict__ scorep, float* __restrict__ wout){
  const int b = blockIdx.x;
  const int t = threadIdx.x;                 // 256
  float v[8];
  #pragma unroll
  for (int i = 0; i < 8; ++i) v[i] = scorep[(size_t)b * SS + t + i * 256];
  float m = v[0];
  #pragma unroll
  for (int i = 1; i < 8; ++i) m = fmaxf(m, v[i]);
  #pragma unroll
  for (int msk = 32; msk >= 1; msk >>= 1) m = fmaxf(m, __shfl_xor(m, msk));
  __shared__ float redm[4], reds[4];
  if ((t & 63) == 0) redm[t >> 6] = m;
  __syncthreads();
  m = fmaxf(fmaxf(redm[0], redm[1]), fmaxf(redm[2], redm[3]));
  float s = 0.f;
  #pragma unroll
  for (int i = 0; i < 8; ++i){ v[i] = __expf(v[i] - m); s += v[i]; }
  #pragma unroll
  for (int msk = 32; msk >= 1; msk >>= 1) s += __shfl_xor(s, msk);
  if ((t & 63) == 0) reds[t >> 6] = s;
  __syncthreads();
  s = reds[0] + reds[1] + reds[2] + reds[3];
  float inv = 1.f / s;
  #pragma unroll
  for (int i = 0; i < 8; ++i) wout[(size_t)b * SS + t + i * 256] = v[i] * inv;
}

// ---- kernel 4: ctx partials (fp32 x, no atomics; HBM-roofline) ----
__global__ void ctx_partial_kernel(const float* __restrict__ x, const float* __restrict__ wout,
                                   float* __restrict__ ctxp){
  __shared__ float red[4][512];
  const int t   = threadIdx.x;
  const int sub = t >> 7;                    // 0..3 (wave-uniform)
  const int dt  = t & 127;                   // d = dt*4
  const int b   = blockIdx.x >> 3;
  const int sc  = blockIdx.x & 7;
  const float* xb = x + (size_t)b * SS * DD;
  const int s0 = sc * 256 + sub * 64;
  float4 acc = {0.f, 0.f, 0.f, 0.f};
  for (int s = s0; s < s0 + 64; ++s){
    float wv = wout[(size_t)b * SS + s];     // wave-uniform -> scalar load
    float4 xv = *(const float4*)(xb + (size_t)s * DD + dt * 4);
    acc.x += wv * xv.x; acc.y += wv * xv.y; acc.z += wv * xv.z; acc.w += wv * xv.w;
  }
  *(float4*)&red[sub][dt * 4] = acc;
  __syncthreads();
  if (t < 128){
    float4 r0 = *(const float4*)&red[0][t * 4];
    float4 r1 = *(const float4*)&red[1][t * 4];
    float4 r2 = *(const float4*)&red[2][t * 4];
    float4 r3 = *(const float4*)&red[3][t * 4];
    float4 o = { r0.x+r1.x+r2.x+r3.x, r0.y+r1.y+r2.y+r3.y,
                 r0.z+r1.z+r2.z+r3.z, r0.w+r1.w+r2.w+r3.w };
    *(float4*)&ctxp[((size_t)(b * 8 + sc)) * DD + t * 4] = o;
  }
}

// ---- kernel 5: reduce ctx partials -> d_out ----
__global__ void ctx_reduce_kernel(const float* __restrict__ ctxp, float* __restrict__ ctx){
  int i = blockIdx.x * blockDim.x + threadIdx.x;   // 32768
  int b = i >> 9;
  int d = i & 511;
  float s = 0.f;
  #pragma unroll
  for (int sc = 0; sc < 8; ++sc) s += ctxp[((size_t)(b * 8 + sc)) * DD + d];
  ctx[(size_t)b * DD + d] = s;
}

extern "C" void kernel_launch(void* const* d_in, const int* in_sizes, int n_in,
                              void* d_out, int out_size, void* d_ws, size_t ws_size,
                              hipStream_t stream){
  const float* x  = (const float*)d_in[0];
  const float* W1 = (const float*)d_in[1];
  const float* b1 = (const float*)d_in[2];
  const float* w2 = (const float*)d_in[3];
  // d_in[4] = b2: softmax-invariant, unused.

  float* ctx  = (float*)d_out;                         // [64*512]
  float* wout = (float*)d_out + BB * DD;               // [64*2048]

  // ws layout (phase-disjoint reuse):
  //   scores phase: W1s [0, 512K), scorep [512K, 1M)
  //   ctx phase:    ctxp [0, 1M)  (W1s/scorep dead by then; same-stream order)
  unsigned short* W1s = (unsigned short*)d_ws;
  float* scorep = (float*)((char*)d_ws + (512u << 10));
  float* ctxp   = (float*)d_ws;

  hipLaunchKernelGGL(cvt_w1_kernel,      dim3(128),  dim3(256), 0, stream, W1, W1s);
  hipLaunchKernelGGL(scores_kernel,      dim3(2048), dim3(512), 0, stream, x, W1s, b1, w2, scorep);
  hipLaunchKernelGGL(softmax_kernel,     dim3(64),   dim3(256), 0, stream, scorep, wout);
  hipLaunchKernelGGL(ctx_partial_kernel, dim3(512),  dim3(512), 0, stream, x, wout, ctxp);
  hipLaunchKernelGGL(ctx_reduce_kernel,  dim3(128),  dim3(256), 0, stream, ctxp, ctx);
}